// Round 1
// baseline (56.690 us; speedup 1.0000x reference)
//
#include <hip/hip_runtime.h>
#include <math.h>

#define NN 20
#define ED 4
#define APAD 21          // padded A row stride (floats) -> conflict-free scalar reads
#define WPN 68           // floats per node in const block: 32 gateR + 32 upd + 4 bias
#define WOFF (NN * APAD) // 420
#define LINOFF (WOFF + NN * WPN) // 1780
#define NCONS (LINOFF + 3)       // 1783
#define BB 64            // batch elements per tile
#define XROW 160         // floats per batch element (20 nodes * 8 feat)
#define XSTRIDE 168      // padded LDS stride (168 % 32 == 8 -> distinct-b lanes distinct banks)
#define THREADS 256
#define PAIRS_PER_TILE (BB * NN)       // 1280
#define F4_PER_TILE (BB * XROW / 4)    // 2560

__global__ void precompute_consts(const float* __restrict__ e,
                                  const float* __restrict__ gate_w,
                                  const float* __restrict__ gate_b,
                                  const float* __restrict__ upd_w,
                                  const float* __restrict__ upd_b,
                                  const float* __restrict__ lin_w,
                                  const float* __restrict__ lin_b,
                                  float* __restrict__ cons) {
    __shared__ float s[NN * NN];
    const int t = threadIdx.x;
    // scores = relu(e @ e^T)
    for (int idx = t; idx < NN * NN; idx += blockDim.x) {
        int n = idx / NN, m = idx % NN;
        float d = 0.f;
        for (int j = 0; j < ED; ++j) d += e[n * ED + j] * e[m * ED + j];
        s[idx] = fmaxf(d, 0.f);
    }
    __syncthreads();
    // row softmax -> A, stored padded stride 21
    if (t < NN) {
        float mx = -1e30f;
        for (int m = 0; m < NN; ++m) mx = fmaxf(mx, s[t * NN + m]);
        float ex[NN];
        float sum = 0.f;
        for (int m = 0; m < NN; ++m) { ex[m] = __expf(s[t * NN + m] - mx); sum += ex[m]; }
        float inv = 1.f / sum;
        for (int m = 0; m < NN; ++m) cons[t * APAD + m] = ex[m] * inv;
    }
    // per-node folded weights. Layout per node n (68 floats):
    //   [0..15]  gate R0 weights, order k*8+i  (o=2 of gate)
    //   [16..31] gate R1 weights               (o=3 of gate)
    //   [32..47] upd  o0 weights
    //   [48..63] upd  o1 weights
    //   [64..67] biases: bR0, bR1, bU0, bU1
    for (int idx = t; idx < NN * WPN; idx += blockDim.x) {
        int n = idx / WPN, r = idx % WPN;
        float v = 0.f;
        if (r < 32) {
            int o = r / 16 + 2, k = (r / 8) & 1, i = r & 7;
            for (int d = 0; d < ED; ++d)
                v += e[n * ED + d] * gate_w[d * 80 + k * 40 + i * 4 + o]; // (4,2,10,4)
        } else if (r < 64) {
            int rr = r - 32;
            int o = rr / 16, k = (rr / 8) & 1, i = rr & 7;
            for (int d = 0; d < ED; ++d)
                v += e[n * ED + d] * upd_w[d * 40 + k * 20 + i * 2 + o]; // (4,2,10,2)
        } else if (r == 64) { for (int d = 0; d < ED; ++d) v += e[n * ED + d] * gate_b[d * 4 + 2]; }
          else if (r == 65) { for (int d = 0; d < ED; ++d) v += e[n * ED + d] * gate_b[d * 4 + 3]; }
          else if (r == 66) { for (int d = 0; d < ED; ++d) v += e[n * ED + d] * upd_b[d * 2 + 0]; }
          else              { for (int d = 0; d < ED; ++d) v += e[n * ED + d] * upd_b[d * 2 + 1]; }
        cons[WOFF + idx] = v;
    }
    if (t == 0) {
        cons[LINOFF + 0] = lin_w[0];
        cons[LINOFF + 1] = lin_w[1];
        cons[LINOFF + 2] = lin_b[0];
    }
}

__device__ __forceinline__ float dot16(const float* __restrict__ w,
                                       float4 xa, float4 xb, float4 ga, float4 gb) {
    float4 w0 = *((const float4*)&w[0]);
    float4 w1 = *((const float4*)&w[4]);
    float4 w2 = *((const float4*)&w[8]);
    float4 w3 = *((const float4*)&w[12]);
    return w0.x * xa.x + w0.y * xa.y + w0.z * xa.z + w0.w * xa.w
         + w1.x * xb.x + w1.y * xb.y + w1.z * xb.z + w1.w * xb.w
         + w2.x * ga.x + w2.y * ga.y + w2.z * ga.z + w2.w * ga.w
         + w3.x * gb.x + w3.y * gb.y + w3.z * gb.z + w3.w * gb.w;
}

__global__ __launch_bounds__(THREADS) void rgcn_main(const float* __restrict__ x,
                                                     const float* __restrict__ consg,
                                                     float* __restrict__ y,
                                                     int ntiles) {
    __shared__ float cons[NCONS + 9];         // pad to keep alignment headroom
    __shared__ float xs[BB * XSTRIDE];        // 10752 floats = 43008 B
    for (int i = threadIdx.x; i < NCONS; i += THREADS) cons[i] = consg[i];
    // (visibility of cons covered by the per-tile barrier below)

    const float4* __restrict__ xg = (const float4*)x;
    for (int tile = blockIdx.x; tile < ntiles; tile += gridDim.x) {
        // stage 64 batch rows into LDS, padded stride
        #pragma unroll
        for (int j = 0; j < F4_PER_TILE / THREADS; ++j) { // 10
            int q = threadIdx.x + j * THREADS;
            float4 v = xg[(size_t)tile * F4_PER_TILE + q];
            int b = q / 40;           // 40 float4 per batch row
            int rr = q - b * 40;
            *((float4*)&xs[b * XSTRIDE + rr * 4]) = v;
        }
        __syncthreads();

        const float lw0 = cons[LINOFF + 0];
        const float lw1 = cons[LINOFF + 1];
        const float lb  = cons[LINOFF + 2];

        #pragma unroll
        for (int kk = 0; kk < PAIRS_PER_TILE / THREADS; ++kk) { // 5
            int p = threadIdx.x + kk * THREADS;
            int b = p / NN;
            int n = p - b * NN;
            const float* __restrict__ xrow = &xs[b * XSTRIDE];
            float4 xa = *((const float4*)&xrow[n * 8]);
            float4 xb = *((const float4*)&xrow[n * 8 + 4]);
            // xg1 = A[n,:] @ x[b,:,:]
            float4 ga = make_float4(0.f, 0.f, 0.f, 0.f);
            float4 gb = make_float4(0.f, 0.f, 0.f, 0.f);
            const float* __restrict__ Arow = &cons[n * APAD];
            #pragma unroll
            for (int m = 0; m < NN; ++m) {
                float am = Arow[m];
                float4 lo = *((const float4*)&xrow[m * 8]);
                float4 hi = *((const float4*)&xrow[m * 8 + 4]);
                ga.x += am * lo.x; ga.y += am * lo.y; ga.z += am * lo.z; ga.w += am * lo.w;
                gb.x += am * hi.x; gb.y += am * hi.y; gb.z += am * hi.z; gb.w += am * hi.w;
            }
            const float* __restrict__ w = &cons[WOFF + n * WPN];
            float r0 = w[64] + dot16(w,      xa, xb, ga, gb);
            float r1 = w[65] + dot16(w + 16, xa, xb, ga, gb);
            float u0 = w[66] + dot16(w + 32, xa, xb, ga, gb);
            float u1 = w[67] + dot16(w + 48, xa, xb, ga, gb);
            // R = sigmoid, HC = tanh, H = (1-R)*HC (H_prev = 0, Z unused)
            r0 = 1.f / (1.f + __expf(-r0));
            r1 = 1.f / (1.f + __expf(-r1));
            float t0 = 1.f - 2.f / (__expf(2.f * u0) + 1.f);
            float t1 = 1.f - 2.f / (__expf(2.f * u1) + 1.f);
            float h0 = (1.f - r0) * t0;
            float h1 = (1.f - r1) * t1;
            float yv = fmaxf(h0, 0.f) * lw0 + fmaxf(h1, 0.f) * lw1 + lb;
            y[(size_t)tile * PAIRS_PER_TILE + p] = yv;
        }
        __syncthreads();
    }
}

extern "C" void kernel_launch(void* const* d_in, const int* in_sizes, int n_in,
                              void* d_out, int out_size, void* d_ws, size_t ws_size,
                              hipStream_t stream) {
    const float* x      = (const float*)d_in[0];
    const float* e      = (const float*)d_in[1];
    const float* gate_w = (const float*)d_in[2];
    const float* gate_b = (const float*)d_in[3];
    const float* upd_w  = (const float*)d_in[4];
    const float* upd_b  = (const float*)d_in[5];
    const float* lin_w  = (const float*)d_in[6];
    const float* lin_b  = (const float*)d_in[7];

    float* cons = (float*)d_ws;
    float* y    = (float*)d_out;

    const int Bn = in_sizes[0] / XROW;   // 131072
    const int ntiles = Bn / BB;          // 2048

    precompute_consts<<<1, 128, 0, stream>>>(e, gate_w, gate_b, upd_w, upd_b,
                                             lin_w, lin_b, cons);
    rgcn_main<<<ntiles, THREADS, 0, stream>>>(x, cons, y, ntiles);
}

// Round 2
// 48.120 us; speedup vs baseline: 1.1781x; 1.1781x over previous
//
#include <hip/hip_runtime.h>
#include <math.h>

#define NN 20
#define ED 4
#define FIN 8
#define XROW 160            // floats per batch row
#define NC 80               // output pre-activations per row (20 nodes * 4)
#define NKT 5               // K tiles of 32 (K=160)
#define NNT 5               // N tiles of 16 (N=80)
#define FRAG_ELEMS (NKT * NNT * 64 * 8)   // 12800 bf16 per (hi|lo)
#define FRAG_BYTES (FRAG_ELEMS * 2)       // 25600
#define BIAS_OFF   (2 * FRAG_BYTES)       // 51200
#define LIN_OFF    (BIAS_OFF + NC * 4)    // 51520
#define CONS_BYTES (LIN_OFF + 16)         // 51536
#define THREADS 512
#define ROWS_PER_WAVE 32
#define ROWS_PER_BLOCK (ROWS_PER_WAVE * (THREADS / 64))  // 256

typedef __attribute__((ext_vector_type(8))) short short8;
typedef __attribute__((ext_vector_type(4))) float f32x4;
typedef __attribute__((ext_vector_type(4))) unsigned uint4v;

static __device__ __forceinline__ unsigned fbits(float x) { return __builtin_bit_cast(unsigned, x); }
static __device__ __forceinline__ float truncbf(float x) {
    return __builtin_bit_cast(float, fbits(x) & 0xffff0000u);
}
static __device__ __forceinline__ unsigned pack_hi(float x, float y) {
    return (fbits(x) >> 16) | (fbits(y) & 0xffff0000u);
}

// ---------------- precompute: fold A + per-node weights into M2 (80x160), ----
// ---------------- store in MFMA B-fragment order as bf16 hi/lo + bias + lin --
__global__ void precompute_consts(const float* __restrict__ e,
                                  const float* __restrict__ gate_w,
                                  const float* __restrict__ gate_b,
                                  const float* __restrict__ upd_w,
                                  const float* __restrict__ upd_b,
                                  const float* __restrict__ lin_w,
                                  const float* __restrict__ lin_b,
                                  char* __restrict__ ws) {
    __shared__ float el[NN * ED];
    __shared__ float A[NN][NN];
    const int t = threadIdx.x;
    if (t < NN * ED) el[t] = e[t];
    __syncthreads();
    if (t < NN * NN) {
        int n = t / NN, m = t % NN;
        float d = 0.f;
        for (int j = 0; j < ED; ++j) d += el[n * ED + j] * el[m * ED + j];
        A[n][m] = fmaxf(d, 0.f);
    }
    __syncthreads();
    if (t < NN) {
        float mx = -1e30f;
        for (int m = 0; m < NN; ++m) mx = fmaxf(mx, A[t][m]);
        float sum = 0.f, ex[NN];
        for (int m = 0; m < NN; ++m) { ex[m] = __expf(A[t][m] - mx); sum += ex[m]; }
        float inv = 1.f / sum;
        for (int m = 0; m < NN; ++m) A[t][m] = ex[m] * inv;
    }
    __syncthreads();

    unsigned short* whi = (unsigned short*)ws;
    unsigned short* wlo = (unsigned short*)(ws + FRAG_BYTES);
    float* wbias = (float*)(ws + BIAS_OFF);
    float* wlin  = (float*)(ws + LIN_OFF);

    // fragment layout: element f = ((kt*NNT + nt)*64 + lane)*8 + j
    // holds M2[c = nt*16 + (lane&15)][k = kt*32 + (lane>>4)*8 + j]
    for (int f = t; f < FRAG_ELEMS; f += blockDim.x) {
        int j    = f & 7;
        int lane = (f >> 3) & 63;
        int tile = f >> 9;
        int kt = tile / NNT, nt = tile % NNT;
        int c = nt * 16 + (lane & 15);
        int k = kt * 32 + ((lane >> 4) << 3) + j;
        int n = c >> 2, ro = c & 3;
        int m = k >> 3, i = k & 7;
        float wself = 0.f, wagg = 0.f;
        if (ro < 2) {
            int o = 2 + ro;  // gate_w (4,2,10,4)
            for (int d = 0; d < ED; ++d) {
                float ev = el[n * ED + d];
                wself += ev * gate_w[d * 80 + i * 4 + o];
                wagg  += ev * gate_w[d * 80 + 40 + i * 4 + o];
            }
        } else {
            int o = ro - 2;  // upd_w (4,2,10,2)
            for (int d = 0; d < ED; ++d) {
                float ev = el[n * ED + d];
                wself += ev * upd_w[d * 40 + i * 2 + o];
                wagg  += ev * upd_w[d * 40 + 20 + i * 2 + o];
            }
        }
        float val = A[n][m] * wagg + (n == m ? wself : 0.f);
        float hi = truncbf(val);
        float lo = val - hi;
        whi[f] = (unsigned short)(fbits(val) >> 16);
        wlo[f] = (unsigned short)(fbits(lo) >> 16);
    }
    if (t < NC) {
        int n = t >> 2, ro = t & 3;
        float b = 0.f;
        for (int d = 0; d < ED; ++d) {
            float ev = el[n * ED + d];
            b += ev * (ro < 2 ? gate_b[d * 4 + 2 + ro] : upd_b[d * 2 + ro - 2]);
        }
        wbias[t] = b;
    }
    if (t == 0) { wlin[0] = lin_w[0]; wlin[1] = lin_w[1]; wlin[2] = lin_b[0]; }
}

// ---------------- main: GEMM (B x 160) * M2^T via bf16 hi/lo MFMA + epilogue -
__global__ __launch_bounds__(THREADS, 4) void rgcn_main(
        const float* __restrict__ x,
        const char* __restrict__ consg,
        float* __restrict__ y) {
    __shared__ __align__(16) char s[CONS_BYTES];
    {
        const uint4v* src = (const uint4v*)consg;
        uint4v* dst = (uint4v*)s;
        for (int i = threadIdx.x; i < CONS_BYTES / 16; i += THREADS) dst[i] = src[i];
    }
    __syncthreads();

    const short8* fhi = (const short8*)s;
    const short8* flo = (const short8*)(s + FRAG_BYTES);
    const float* sbias = (const float*)(s + BIAS_OFF);
    const float* slin  = (const float*)(s + LIN_OFF);

    const int l = threadIdx.x & 63;
    const int w = threadIdx.x >> 6;
    const size_t row0 = (size_t)blockIdx.x * ROWS_PER_BLOCK + (size_t)w * ROWS_PER_WAVE;

    const float* xp0 = x + (row0 + (l & 15)) * XROW + ((l >> 4) << 3);
    const float* xp1 = xp0 + (size_t)16 * XROW;

    f32x4 acc[2][NNT];
    #pragma unroll
    for (int mt = 0; mt < 2; ++mt)
        #pragma unroll
        for (int nt = 0; nt < NNT; ++nt) acc[mt][nt] = (f32x4){0.f, 0.f, 0.f, 0.f};

    #pragma unroll
    for (int kt = 0; kt < NKT; ++kt) {
        float4 xa0 = *(const float4*)(xp0 + kt * 32);
        float4 xb0 = *(const float4*)(xp0 + kt * 32 + 4);
        float4 xa1 = *(const float4*)(xp1 + kt * 32);
        float4 xb1 = *(const float4*)(xp1 + kt * 32 + 4);

        short8 ahi0 = __builtin_bit_cast(short8, (uint4v){
            pack_hi(xa0.x, xa0.y), pack_hi(xa0.z, xa0.w),
            pack_hi(xb0.x, xb0.y), pack_hi(xb0.z, xb0.w)});
        short8 alo0 = __builtin_bit_cast(short8, (uint4v){
            pack_hi(xa0.x - truncbf(xa0.x), xa0.y - truncbf(xa0.y)),
            pack_hi(xa0.z - truncbf(xa0.z), xa0.w - truncbf(xa0.w)),
            pack_hi(xb0.x - truncbf(xb0.x), xb0.y - truncbf(xb0.y)),
            pack_hi(xb0.z - truncbf(xb0.z), xb0.w - truncbf(xb0.w))});
        short8 ahi1 = __builtin_bit_cast(short8, (uint4v){
            pack_hi(xa1.x, xa1.y), pack_hi(xa1.z, xa1.w),
            pack_hi(xb1.x, xb1.y), pack_hi(xb1.z, xb1.w)});
        short8 alo1 = __builtin_bit_cast(short8, (uint4v){
            pack_hi(xa1.x - truncbf(xa1.x), xa1.y - truncbf(xa1.y)),
            pack_hi(xa1.z - truncbf(xa1.z), xa1.w - truncbf(xa1.w)),
            pack_hi(xb1.x - truncbf(xb1.x), xb1.y - truncbf(xb1.y)),
            pack_hi(xb1.z - truncbf(xb1.z), xb1.w - truncbf(xb1.w))});

        #pragma unroll
        for (int nt = 0; nt < NNT; ++nt) {
            short8 bh = fhi[(kt * NNT + nt) * 64 + l];
            short8 bl = flo[(kt * NNT + nt) * 64 + l];
            acc[0][nt] = __builtin_amdgcn_mfma_f32_16x16x32_bf16(ahi0, bh, acc[0][nt], 0, 0, 0);
            acc[0][nt] = __builtin_amdgcn_mfma_f32_16x16x32_bf16(alo0, bh, acc[0][nt], 0, 0, 0);
            acc[0][nt] = __builtin_amdgcn_mfma_f32_16x16x32_bf16(ahi0, bl, acc[0][nt], 0, 0, 0);
            acc[1][nt] = __builtin_amdgcn_mfma_f32_16x16x32_bf16(ahi1, bh, acc[1][nt], 0, 0, 0);
            acc[1][nt] = __builtin_amdgcn_mfma_f32_16x16x32_bf16(alo1, bh, acc[1][nt], 0, 0, 0);
            acc[1][nt] = __builtin_amdgcn_mfma_f32_16x16x32_bf16(ahi1, bl, acc[1][nt], 0, 0, 0);
        }
    }

    // epilogue: C/D layout col = l&15, row = (l>>4)*4 + q
    const float lw0 = slin[0], lw1 = slin[1], lb = slin[2];
    const int ro = l & 3;                 // c & 3
    const bool isR = ro < 2;
    const float lw = (ro & 1) ? lw1 : lw0;

    #pragma unroll
    for (int mt = 0; mt < 2; ++mt) {
        const size_t rowbase = row0 + mt * 16 + ((l >> 4) << 2);
        #pragma unroll
        for (int nt = 0; nt < NNT; ++nt) {
            const int c = nt * 16 + (l & 15);
            const int n = c >> 2;
            const float bia = sbias[c];
            #pragma unroll
            for (int q = 0; q < 4; ++q) {
                float pre = acc[mt][nt][q] + bia;
                float z = isR ? pre : 2.f * pre;
                float ev = __expf(z);
                // lanes ro<2: (1 - sigmoid(pre)) = 1/(1+exp(pre)); else tanh(pre)
                float a = isR ? (1.f / (1.f + ev)) : (1.f - 2.f / (ev + 1.f));
                float pm = __shfl_xor(a, 2);
                float h = a * pm;                      // h0 on ro=0, h1 on ro=1
                float yt = fmaxf(h, 0.f) * lw;
                float y2 = __shfl_xor(yt, 1);
                float yv = yt + y2 + lb;
                if (ro == 0) y[(rowbase + q) * NN + n] = yv;
            }
        }
    }
}

extern "C" void kernel_launch(void* const* d_in, const int* in_sizes, int n_in,
                              void* d_out, int out_size, void* d_ws, size_t ws_size,
                              hipStream_t stream) {
    const float* x      = (const float*)d_in[0];
    const float* e      = (const float*)d_in[1];
    const float* gate_w = (const float*)d_in[2];
    const float* gate_b = (const float*)d_in[3];
    const float* upd_w  = (const float*)d_in[4];
    const float* upd_b  = (const float*)d_in[5];
    const float* lin_w  = (const float*)d_in[6];
    const float* lin_b  = (const float*)d_in[7];

    char* cons = (char*)d_ws;
    float* y   = (float*)d_out;

    const int Bn = in_sizes[0] / XROW;            // 131072
    const int nblocks = Bn / ROWS_PER_BLOCK;      // 512

    precompute_consts<<<1, 512, 0, stream>>>(e, gate_w, gate_b, upd_w, upd_b,
                                             lin_w, lin_b, cons);
    rgcn_main<<<nblocks, THREADS, 0, stream>>>(x, cons, y);
}

// Round 3
// 33.932 us; speedup vs baseline: 1.6707x; 1.4181x over previous
//
#include <hip/hip_runtime.h>
#include <math.h>

#define NN 20
#define ED 4
#define XROW 160            // floats per batch row
#define NC 80               // pre-activations per row (20 nodes * 4)
#define NKT 5               // K tiles of 32 (K=160)
#define NNT 5               // N tiles of 16 (N=80)
#define FRAG_ELEMS (NKT * NNT * 64 * 8)   // 12800 bf16 per (hi|lo)
#define FRAG_BYTES (FRAG_ELEMS * 2)       // 25600
#define BIAS_OFF   (2 * FRAG_BYTES)       // 51200 (bytes)
#define LIN_OFF    (BIAS_OFF + NC * 4)    // 51520
#define CONS_BYTES (LIN_OFF + 16)         // 51536
#define THREADS 512
#define ROWS_PER_WAVE 64
#define ROWS_PER_BLOCK 512
#define EPI_STRIDE 84       // floats; 128*84*4 = 43008 B <= 51200 (fits under bias)

typedef __attribute__((ext_vector_type(8))) short short8;
typedef __attribute__((ext_vector_type(4))) float f32x4;
typedef __attribute__((ext_vector_type(4))) unsigned uint4v;

static __device__ __forceinline__ unsigned fbits(float x) { return __builtin_bit_cast(unsigned, x); }
static __device__ __forceinline__ float truncbf(float x) {
    return __builtin_bit_cast(float, fbits(x) & 0xffff0000u);
}
static __device__ __forceinline__ unsigned pack_hi(float x, float y) {
    return (fbits(x) >> 16) | (fbits(y) & 0xffff0000u);
}

__global__ __launch_bounds__(THREADS, 2) void rgcn_fused(
        const float* __restrict__ x,
        const float* __restrict__ e,
        const float* __restrict__ gate_w,
        const float* __restrict__ gate_b,
        const float* __restrict__ upd_w,
        const float* __restrict__ upd_b,
        const float* __restrict__ lin_w,
        const float* __restrict__ lin_b,
        float* __restrict__ y) {
    __shared__ __align__(16) char smem[CONS_BYTES];   // frags + bias + lin; frag part reused by epilogue
    __shared__ float sset[2264];                      // setup scratch
    float* el    = sset;          // 80
    float* sA    = sset + 80;     // 400 (scores -> A)
    float* wself = sset + 480;    // 640 [c*8+i]
    float* wagg  = sset + 1120;   // 640
    float* gw    = sset + 1760;   // 320
    float* gb    = sset + 2080;   // 16
    float* uw    = sset + 2096;   // 160
    float* ub    = sset + 2256;   // 8

    const int t = threadIdx.x;
    const int l = t & 63;
    const int w = t >> 6;

    // ---- phase 1: stage raw params into LDS ----
    if (t < 80) el[t] = e[t];
    else if (t < 400) gw[t - 80] = gate_w[t - 80];
    else if (t < 416) gb[t - 400] = gate_b[t - 400];
    else if (t < 424) ub[t - 416] = upd_b[t - 416];
    if (t < 160) uw[t] = upd_w[t];
    __syncthreads();

    // ---- phase 2: relu(e e^T) scores + folded per-(c,i) weights + bias/lin ----
    if (t < 400) {
        int n = t / 20, m = t - (t / 20) * 20;
        float d = 0.f;
        for (int j = 0; j < ED; ++j) d += el[n * ED + j] * el[m * ED + j];
        sA[t] = fmaxf(d, 0.f);
    }
    for (int idx = t; idx < 1280; idx += THREADS) {
        int sel = idx >= 640;              // 0: self (k=0), 1: agg (k=1)
        int rem = sel ? idx - 640 : idx;
        int c = rem >> 3, i = rem & 7;
        int n = c >> 2, ro = c & 3;
        float v = 0.f;
        if (ro < 2) {
            int o = 2 + ro;                // R part of gate
            for (int d = 0; d < ED; ++d) v += el[n * ED + d] * gw[d * 80 + sel * 40 + i * 4 + o];
        } else {
            int o = ro - 2;
            for (int d = 0; d < ED; ++d) v += el[n * ED + d] * uw[d * 40 + sel * 20 + i * 2 + o];
        }
        (sel ? wagg : wself)[rem] = v;
    }
    float* sbias = (float*)(smem + BIAS_OFF);
    float* slin  = (float*)(smem + LIN_OFF);
    if (t < NC) {
        int n = t >> 2, ro = t & 3;
        float b = 0.f;
        for (int d = 0; d < ED; ++d)
            b += el[n * ED + d] * (ro < 2 ? gb[d * 4 + 2 + ro] : ub[d * 2 + ro - 2]);
        sbias[t] = b;
    }
    if (t == 0) { slin[0] = lin_w[0]; slin[1] = lin_w[1]; slin[2] = lin_b[0]; }
    __syncthreads();

    // ---- phase 3: row softmax -> A (in place in sA) ----
    if (t < NN) {
        float mx = -1e30f;
        for (int m = 0; m < NN; ++m) mx = fmaxf(mx, sA[t * 20 + m]);
        float ex[NN]; float sum = 0.f;
        for (int m = 0; m < NN; ++m) { ex[m] = __expf(sA[t * 20 + m] - mx); sum += ex[m]; }
        float inv = 1.f / sum;
        for (int m = 0; m < NN; ++m) sA[t * 20 + m] = ex[m] * inv;
    }
    __syncthreads();

    // ---- phase 4: build bf16 hi/lo B-fragments in MFMA order ----
    // element f = (tile*64 + lane)*8 + j holds M2[c = nt*16+(lane&15)][k = kt*32+(lane>>4)*8+j]
    {
        unsigned short* whi = (unsigned short*)smem;
        unsigned short* wlo = (unsigned short*)(smem + FRAG_BYTES);
        for (int tile = w; tile < NKT * NNT; tile += 8) {
            int kt = tile / 5, nt = tile - kt * 5;
            int c = nt * 16 + (l & 15);
            int n = c >> 2;
            int kbase = kt * 32 + ((l >> 4) << 3);
            #pragma unroll
            for (int j = 0; j < 8; ++j) {
                int k = kbase + j;
                int m = k >> 3, i = k & 7;
                float val = sA[n * 20 + m] * wagg[c * 8 + i] + (n == m ? wself[c * 8 + i] : 0.f);
                float lo = val - truncbf(val);
                int f = (tile * 64 + l) * 8 + j;
                whi[f] = (unsigned short)(fbits(val) >> 16);
                wlo[f] = (unsigned short)(fbits(lo) >> 16);
            }
        }
    }
    __syncthreads();

    // ---- main GEMM: 64 rows/wave, bf16 hi/lo split, 300 MFMAs ----
    const short8* fhi = (const short8*)smem;
    const short8* flo = (const short8*)(smem + FRAG_BYTES);
    const size_t row0 = (size_t)blockIdx.x * ROWS_PER_BLOCK + (size_t)w * ROWS_PER_WAVE;

    const float* xq[4];
    #pragma unroll
    for (int g = 0; g < 4; ++g)
        xq[g] = x + (row0 + g * 16 + (l & 15)) * XROW + ((l >> 4) << 3);

    f32x4 acc[4][NNT];
    #pragma unroll
    for (int g = 0; g < 4; ++g)
        #pragma unroll
        for (int nt = 0; nt < NNT; ++nt) acc[g][nt] = (f32x4){0.f, 0.f, 0.f, 0.f};

    #pragma unroll
    for (int kt = 0; kt < NKT; ++kt) {
        short8 ah[4], al[4];
        #pragma unroll
        for (int g = 0; g < 4; ++g) {
            float4 xa = *(const float4*)(xq[g] + kt * 32);
            float4 xb = *(const float4*)(xq[g] + kt * 32 + 4);
            ah[g] = __builtin_bit_cast(short8, (uint4v){
                pack_hi(xa.x, xa.y), pack_hi(xa.z, xa.w),
                pack_hi(xb.x, xb.y), pack_hi(xb.z, xb.w)});
            al[g] = __builtin_bit_cast(short8, (uint4v){
                pack_hi(xa.x - truncbf(xa.x), xa.y - truncbf(xa.y)),
                pack_hi(xa.z - truncbf(xa.z), xa.w - truncbf(xa.w)),
                pack_hi(xb.x - truncbf(xb.x), xb.y - truncbf(xb.y)),
                pack_hi(xb.z - truncbf(xb.z), xb.w - truncbf(xb.w))});
        }
        #pragma unroll
        for (int nt = 0; nt < NNT; ++nt) {
            short8 bh = fhi[(kt * NNT + nt) * 64 + l];
            short8 bl = flo[(kt * NNT + nt) * 64 + l];
            #pragma unroll
            for (int g = 0; g < 4; ++g) {
                acc[g][nt] = __builtin_amdgcn_mfma_f32_16x16x32_bf16(ah[g], bh, acc[g][nt], 0, 0, 0);
                acc[g][nt] = __builtin_amdgcn_mfma_f32_16x16x32_bf16(al[g], bh, acc[g][nt], 0, 0, 0);
                acc[g][nt] = __builtin_amdgcn_mfma_f32_16x16x32_bf16(ah[g], bl, acc[g][nt], 0, 0, 0);
            }
        }
    }

    // ---- epilogue: restage pre-acts in LDS (reuse frag region), coalesced stores ----
    const float lw0 = slin[0], lw1 = slin[1], lb = slin[2];
    __syncthreads();                     // all frag reads done before overwrite
    float* epi = (float*)smem;
    #pragma unroll
    for (int mt = 0; mt < 4; ++mt) {
        // pass 1: write pre+bias for this 16-row group of every wave (128 rows)
        #pragma unroll
        for (int nt = 0; nt < NNT; ++nt) {
            int c = nt * 16 + (l & 15);
            float bia = sbias[c];
            #pragma unroll
            for (int q = 0; q < 4; ++q) {
                int rc = w * 16 + ((l >> 4) << 2) + q;   // compact row 0..127
                epi[rc * EPI_STRIDE + c] = acc[mt][nt][q] + bia;
            }
        }
        __syncthreads();
        // pass 2: activations + coalesced store (2560 outputs)
        #pragma unroll
        for (int j = 0; j < 5; ++j) {
            int o = t + j * THREADS;
            int rc = o / 20;
            int n = o - rc * 20;
            float4 p = *(const float4*)&epi[rc * EPI_STRIDE + n * 4];
            // h = (1 - sigmoid(pre_R)) * tanh(pre_U)
            float i0 = 1.f / (1.f + __expf(p.x));
            float i1 = 1.f / (1.f + __expf(p.y));
            float t0 = 1.f - 2.f / (__expf(2.f * p.z) + 1.f);
            float t1 = 1.f - 2.f / (__expf(2.f * p.w) + 1.f);
            float h0 = i0 * t0;
            float h1 = i1 * t1;
            float yv = fmaxf(h0, 0.f) * lw0 + fmaxf(h1, 0.f) * lw1 + lb;
            size_t g = (size_t)blockIdx.x * ROWS_PER_BLOCK + (size_t)(rc >> 4) * 64 + mt * 16 + (rc & 15);
            y[g * NN + n] = yv;
        }
        __syncthreads();
    }
}

extern "C" void kernel_launch(void* const* d_in, const int* in_sizes, int n_in,
                              void* d_out, int out_size, void* d_ws, size_t ws_size,
                              hipStream_t stream) {
    const float* x      = (const float*)d_in[0];
    const float* e      = (const float*)d_in[1];
    const float* gate_w = (const float*)d_in[2];
    const float* gate_b = (const float*)d_in[3];
    const float* upd_w  = (const float*)d_in[4];
    const float* upd_b  = (const float*)d_in[5];
    const float* lin_w  = (const float*)d_in[6];
    const float* lin_b  = (const float*)d_in[7];
    float* y = (float*)d_out;

    const int Bn = in_sizes[0] / XROW;           // 131072
    const int nblocks = Bn / ROWS_PER_BLOCK;     // 256

    rgcn_fused<<<nblocks, THREADS, 0, stream>>>(x, e, gate_w, gate_b,
                                                upd_w, upd_b, lin_w, lin_b, y);
}

// Round 4
// 32.123 us; speedup vs baseline: 1.7648x; 1.0563x over previous
//
#include <hip/hip_runtime.h>
#include <math.h>

#define NN 20
#define ED 4
#define XROW 160            // floats per batch row
#define NC 80               // pre-activations per row (20 nodes * 4)
#define NKT 5               // K tiles of 32 (K=160)
#define NNT 5               // N tiles of 16 (N=80)
#define FRAG_ELEMS (NKT * NNT * 64 * 8)   // 12800 bf16 per (hi|lo)
#define FRAG_BYTES (FRAG_ELEMS * 2)       // 25600
#define BIAS_OFF   (2 * FRAG_BYTES)       // 51200 (bytes)
#define LIN_OFF    (BIAS_OFF + NC * 4)    // 51520
#define CONS_BYTES (LIN_OFF + 16)         // 51536
#define THREADS 512
#define ROWS_PER_WAVE 32
#define ROWS_PER_BLOCK 256                // 8 waves * 32 rows
#define EPI_STRIDE 84                     // floats; 128*84*4 = 43008 B < 51200

typedef __attribute__((ext_vector_type(8))) short short8;
typedef __attribute__((ext_vector_type(4))) float f32x4;
typedef __attribute__((ext_vector_type(4))) unsigned uint4v;

static __device__ __forceinline__ unsigned fbits(float x) { return __builtin_bit_cast(unsigned, x); }
static __device__ __forceinline__ float truncbf(float x) {
    return __builtin_bit_cast(float, fbits(x) & 0xffff0000u);
}
static __device__ __forceinline__ unsigned pack_hi(float x, float y) {
    return (fbits(x) >> 16) | (fbits(y) & 0xffff0000u);
}

static __device__ __forceinline__ short8 pack8_hi(float4 a, float4 b) {
    return __builtin_bit_cast(short8, (uint4v){
        pack_hi(a.x, a.y), pack_hi(a.z, a.w),
        pack_hi(b.x, b.y), pack_hi(b.z, b.w)});
}
static __device__ __forceinline__ short8 pack8_lo(float4 a, float4 b) {
    return __builtin_bit_cast(short8, (uint4v){
        pack_hi(a.x - truncbf(a.x), a.y - truncbf(a.y)),
        pack_hi(a.z - truncbf(a.z), a.w - truncbf(a.w)),
        pack_hi(b.x - truncbf(b.x), b.y - truncbf(b.y)),
        pack_hi(b.z - truncbf(b.z), b.w - truncbf(b.w))});
}

__global__ __launch_bounds__(THREADS, 4) void rgcn_fused(
        const float* __restrict__ x,
        const float* __restrict__ e,
        const float* __restrict__ gate_w,
        const float* __restrict__ gate_b,
        const float* __restrict__ upd_w,
        const float* __restrict__ upd_b,
        const float* __restrict__ lin_w,
        const float* __restrict__ lin_b,
        float* __restrict__ y) {
    __shared__ __align__(16) char smem[CONS_BYTES];   // frags + bias + lin; frag region reused by epilogue
    __shared__ float sset[1760];                      // el(80) sA(400) wself(640) wagg(640)
    float* el    = sset;
    float* sA    = sset + 80;
    float* wself = sset + 480;
    float* wagg  = sset + 1120;

    const int t = threadIdx.x;
    const int l = t & 63;
    const int w = t >> 6;

    // ---- phase 1: stage e ----
    if (t < NN * ED) el[t] = e[t];
    __syncthreads();

    // ---- phase 2: scores + folded per-(c,i) weights (params direct from global) ----
    if (t < 400) {
        int n = t / 20, m = t - (t / 20) * 20;
        float d = 0.f;
        for (int j = 0; j < ED; ++j) d += el[n * ED + j] * el[m * ED + j];
        sA[t] = fmaxf(d, 0.f);
    }
    for (int idx = t; idx < 1280; idx += THREADS) {
        int sel = idx >= 640;              // 0: self (k=0), 1: agg (k=1)
        int rem = sel ? idx - 640 : idx;
        int c = rem >> 3, i = rem & 7;
        int n = c >> 2, ro = c & 3;
        float v = 0.f;
        if (ro < 2) {
            int o = 2 + ro;                // R part of gate
            for (int d = 0; d < ED; ++d) v += el[n * ED + d] * gate_w[d * 80 + sel * 40 + i * 4 + o];
        } else {
            int o = ro - 2;
            for (int d = 0; d < ED; ++d) v += el[n * ED + d] * upd_w[d * 40 + sel * 20 + i * 2 + o];
        }
        (sel ? wagg : wself)[rem] = v;
    }
    float* sbias = (float*)(smem + BIAS_OFF);
    float* slin  = (float*)(smem + LIN_OFF);
    if (t < NC) {
        int n = t >> 2, ro = t & 3;
        float b = 0.f;
        for (int d = 0; d < ED; ++d)
            b += el[n * ED + d] * (ro < 2 ? gate_b[d * 4 + 2 + ro] : upd_b[d * 2 + ro - 2]);
        sbias[t] = b;
    }
    if (t == 0) { slin[0] = lin_w[0]; slin[1] = lin_w[1]; slin[2] = lin_b[0]; }
    __syncthreads();

    // ---- phase 3: row softmax -> A (in place) ----
    if (t < NN) {
        float mx = -1e30f;
        for (int m = 0; m < NN; ++m) mx = fmaxf(mx, sA[t * 20 + m]);
        float ex[NN]; float sum = 0.f;
        for (int m = 0; m < NN; ++m) { ex[m] = __expf(sA[t * 20 + m] - mx); sum += ex[m]; }
        float inv = 1.f / sum;
        for (int m = 0; m < NN; ++m) sA[t * 20 + m] = ex[m] * inv;
    }
    __syncthreads();

    // ---- phase 4: build bf16 hi/lo B-fragments in MFMA order ----
    {
        unsigned short* whi = (unsigned short*)smem;
        unsigned short* wlo = (unsigned short*)(smem + FRAG_BYTES);
        for (int tile = w; tile < NKT * NNT; tile += 8) {
            int kt = tile / 5, nt = tile - kt * 5;
            int c = nt * 16 + (l & 15);
            int n = c >> 2;
            int kbase = kt * 32 + ((l >> 4) << 3);
            #pragma unroll
            for (int j = 0; j < 8; ++j) {
                int k = kbase + j;
                int m = k >> 3, i = k & 7;
                float val = sA[n * 20 + m] * wagg[c * 8 + i] + (n == m ? wself[c * 8 + i] : 0.f);
                float lo = val - truncbf(val);
                int f = (tile * 64 + l) * 8 + j;
                whi[f] = (unsigned short)(fbits(val) >> 16);
                wlo[f] = (unsigned short)(fbits(lo) >> 16);
            }
        }
    }
    __syncthreads();

    // ---- main GEMM: 32 rows/wave (2 M-groups), bf16 hi/lo split, 150 MFMAs ----
    const short8* fhi = (const short8*)smem;
    const short8* flo = (const short8*)(smem + FRAG_BYTES);
    const size_t row0 = (size_t)blockIdx.x * ROWS_PER_BLOCK + (size_t)w * ROWS_PER_WAVE;

    const float* xq0 = x + (row0 + (l & 15)) * XROW + ((l >> 4) << 3);
    const float* xq1 = xq0 + (size_t)16 * XROW;

    f32x4 acc[2][NNT];
    #pragma unroll
    for (int g = 0; g < 2; ++g)
        #pragma unroll
        for (int nt = 0; nt < NNT; ++nt) acc[g][nt] = (f32x4){0.f, 0.f, 0.f, 0.f};

    // register-double-buffered x loads across kt
    float4 pa0 = *(const float4*)(xq0);
    float4 pb0 = *(const float4*)(xq0 + 4);
    float4 pa1 = *(const float4*)(xq1);
    float4 pb1 = *(const float4*)(xq1 + 4);

    #pragma unroll
    for (int kt = 0; kt < NKT; ++kt) {
        float4 na0, nb0, na1, nb1;
        if (kt < NKT - 1) {
            na0 = *(const float4*)(xq0 + (kt + 1) * 32);
            nb0 = *(const float4*)(xq0 + (kt + 1) * 32 + 4);
            na1 = *(const float4*)(xq1 + (kt + 1) * 32);
            nb1 = *(const float4*)(xq1 + (kt + 1) * 32 + 4);
        }
        short8 ah0 = pack8_hi(pa0, pb0);
        short8 al0 = pack8_lo(pa0, pb0);
        short8 ah1 = pack8_hi(pa1, pb1);
        short8 al1 = pack8_lo(pa1, pb1);

        #pragma unroll
        for (int nt = 0; nt < NNT; ++nt) {
            short8 bh = fhi[(kt * NNT + nt) * 64 + l];
            short8 bl = flo[(kt * NNT + nt) * 64 + l];
            acc[0][nt] = __builtin_amdgcn_mfma_f32_16x16x32_bf16(ah0, bh, acc[0][nt], 0, 0, 0);
            acc[0][nt] = __builtin_amdgcn_mfma_f32_16x16x32_bf16(al0, bh, acc[0][nt], 0, 0, 0);
            acc[0][nt] = __builtin_amdgcn_mfma_f32_16x16x32_bf16(ah0, bl, acc[0][nt], 0, 0, 0);
            acc[1][nt] = __builtin_amdgcn_mfma_f32_16x16x32_bf16(ah1, bh, acc[1][nt], 0, 0, 0);
            acc[1][nt] = __builtin_amdgcn_mfma_f32_16x16x32_bf16(al1, bh, acc[1][nt], 0, 0, 0);
            acc[1][nt] = __builtin_amdgcn_mfma_f32_16x16x32_bf16(ah1, bl, acc[1][nt], 0, 0, 0);
        }
        pa0 = na0; pb0 = nb0; pa1 = na1; pb1 = nb1;
    }

    // ---- epilogue: restage pre-acts in LDS (reuse frag region), coalesced stores ----
    const float lw0 = slin[0], lw1 = slin[1], lb = slin[2];
    __syncthreads();                     // all frag reads done before overwrite
    float* epi = (float*)smem;
    #pragma unroll
    for (int mt = 0; mt < 2; ++mt) {
        #pragma unroll
        for (int nt = 0; nt < NNT; ++nt) {
            int c = nt * 16 + (l & 15);
            float bia = sbias[c];
            #pragma unroll
            for (int q = 0; q < 4; ++q) {
                int rc = w * 16 + ((l >> 4) << 2) + q;   // compact row 0..127
                epi[rc * EPI_STRIDE + c] = acc[mt][nt][q] + bia;
            }
        }
        __syncthreads();
        #pragma unroll
        for (int j = 0; j < 5; ++j) {
            int o = t + j * THREADS;
            int rc = o / 20;
            int n = o - rc * 20;
            float4 p = *(const float4*)&epi[rc * EPI_STRIDE + n * 4];
            float i0 = 1.f / (1.f + __expf(p.x));
            float i1 = 1.f / (1.f + __expf(p.y));
            float t0 = 1.f - 2.f / (__expf(2.f * p.z) + 1.f);
            float t1 = 1.f - 2.f / (__expf(2.f * p.w) + 1.f);
            float h0 = i0 * t0;
            float h1 = i1 * t1;
            float yv = fmaxf(h0, 0.f) * lw0 + fmaxf(h1, 0.f) * lw1 + lb;
            size_t g = (size_t)blockIdx.x * ROWS_PER_BLOCK + (size_t)(rc >> 4) * ROWS_PER_WAVE
                     + (size_t)mt * 16 + (rc & 15);
            y[g * NN + n] = yv;
        }
        __syncthreads();
    }
}

extern "C" void kernel_launch(void* const* d_in, const int* in_sizes, int n_in,
                              void* d_out, int out_size, void* d_ws, size_t ws_size,
                              hipStream_t stream) {
    const float* x      = (const float*)d_in[0];
    const float* e      = (const float*)d_in[1];
    const float* gate_w = (const float*)d_in[2];
    const float* gate_b = (const float*)d_in[3];
    const float* upd_w  = (const float*)d_in[4];
    const float* upd_b  = (const float*)d_in[5];
    const float* lin_w  = (const float*)d_in[6];
    const float* lin_b  = (const float*)d_in[7];
    float* y = (float*)d_out;

    const int Bn = in_sizes[0] / XROW;           // 131072
    const int nblocks = Bn / ROWS_PER_BLOCK;     // 512

    rgcn_fused<<<nblocks, THREADS, 0, stream>>>(x, e, gate_w, gate_b,
                                                upd_w, upd_b, lin_w, lin_b, y);
}

// Round 5
// 30.397 us; speedup vs baseline: 1.8650x; 1.0568x over previous
//
#include <hip/hip_runtime.h>
#include <math.h>

#define NN 20
#define ED 4
#define XROW 160            // floats per batch row
#define NC 80               // pre-activations per row (20 nodes * 4)
#define NKT 5               // K tiles of 32 (K=160)
#define NNT 5               // N tiles of 16 (N=80)
#define FRAG_BYTES (NKT * NNT * 64 * 16)  // 25 tiles * 64 lanes * 16 B = 25600
#define SSET_OFF   FRAG_BYTES             // setup scratch floats start (byte offset)
#define EPI_ROWS 128
#define EPI_STRIDE 84                     // floats
#define EPI_BYTES (EPI_ROWS * EPI_STRIDE * 4)  // 43008
#define BIAS_OFF   EPI_BYTES              // 43008 (outside epi region)
#define LIN_OFF    (BIAS_OFF + NC * 4)    // 43328
#define SMEM_BYTES (LIN_OFF + 16)         // 43344
#define THREADS 1024
#define ROWS_PER_WAVE 32
#define ROWS_PER_BLOCK 512                // 16 waves * 32 rows

typedef __attribute__((ext_vector_type(8))) _Float16 half8;
typedef __attribute__((ext_vector_type(4))) float f32x4;
typedef __attribute__((ext_vector_type(4))) unsigned uint4v;

static __device__ __forceinline__ half8 cvt8(float4 a, float4 b) {
    half8 r;
    r[0] = (_Float16)a.x; r[1] = (_Float16)a.y; r[2] = (_Float16)a.z; r[3] = (_Float16)a.w;
    r[4] = (_Float16)b.x; r[5] = (_Float16)b.y; r[6] = (_Float16)b.z; r[7] = (_Float16)b.w;
    return r;
}

__global__ __launch_bounds__(THREADS, 4) void rgcn_fused(
        const float* __restrict__ x,
        const float* __restrict__ e,
        const float* __restrict__ gate_w,
        const float* __restrict__ gate_b,
        const float* __restrict__ upd_w,
        const float* __restrict__ upd_b,
        const float* __restrict__ lin_w,
        const float* __restrict__ lin_b,
        float* __restrict__ y) {
    __shared__ __align__(16) char smem[SMEM_BYTES];
    float* sset  = (float*)(smem + SSET_OFF);  // overlaps epi region; dead before epilogue
    float* el    = sset;          // 80
    float* sA    = sset + 80;     // 400
    float* wself = sset + 480;    // 640 [c*8+i]
    float* wagg  = sset + 1120;   // 640
    float* sbias = (float*)(smem + BIAS_OFF);
    float* slin  = (float*)(smem + LIN_OFF);

    const int t = threadIdx.x;
    const int l = t & 63;
    const int w = t >> 6;

    // ---- issue first-kt x loads early: latency hides under setup ----
    const size_t row0 = (size_t)blockIdx.x * ROWS_PER_BLOCK + (size_t)w * ROWS_PER_WAVE;
    const float* xq0 = x + (row0 + (l & 15)) * XROW + ((l >> 4) << 3);
    const float* xq1 = xq0 + (size_t)16 * XROW;
    float4 pa0 = *(const float4*)(xq0);
    float4 pb0 = *(const float4*)(xq0 + 4);
    float4 pa1 = *(const float4*)(xq1);
    float4 pb1 = *(const float4*)(xq1 + 4);

    // ---- phase 1: stage e ----
    if (t < NN * ED) el[t] = e[t];
    __syncthreads();

    // ---- phase 2: scores + folded per-(c,i) weights + bias/lin ----
    if (t < 400) {
        int n = t / 20, m = t - (t / 20) * 20;
        float d = 0.f;
        for (int j = 0; j < ED; ++j) d += el[n * ED + j] * el[m * ED + j];
        sA[t] = fmaxf(d, 0.f);
    }
    for (int idx = t; idx < 1280; idx += THREADS) {
        int sel = idx >= 640;              // 0: self (k=0), 1: agg (k=1)
        int rem = sel ? idx - 640 : idx;
        int c = rem >> 3, i = rem & 7;
        int n = c >> 2, ro = c & 3;
        float v = 0.f;
        if (ro < 2) {
            int o = 2 + ro;                // R part of gate
            for (int d = 0; d < ED; ++d) v += el[n * ED + d] * gate_w[d * 80 + sel * 40 + i * 4 + o];
        } else {
            int o = ro - 2;
            for (int d = 0; d < ED; ++d) v += el[n * ED + d] * upd_w[d * 40 + sel * 20 + i * 2 + o];
        }
        (sel ? wagg : wself)[rem] = v;
    }
    if (t < NC) {
        int n = t >> 2, ro = t & 3;
        float b = 0.f;
        for (int d = 0; d < ED; ++d)
            b += el[n * ED + d] * (ro < 2 ? gate_b[d * 4 + 2 + ro] : upd_b[d * 2 + ro - 2]);
        sbias[t] = b;
    }
    if (t == 0) { slin[0] = lin_w[0]; slin[1] = lin_w[1]; slin[2] = lin_b[0]; }
    __syncthreads();

    // ---- phase 3: row softmax -> A (in place in sA) ----
    if (t < NN) {
        float mx = -1e30f;
        for (int m = 0; m < NN; ++m) mx = fmaxf(mx, sA[t * 20 + m]);
        float ex[NN]; float sum = 0.f;
        for (int m = 0; m < NN; ++m) { ex[m] = __expf(sA[t * 20 + m] - mx); sum += ex[m]; }
        float inv = 1.f / sum;
        for (int m = 0; m < NN; ++m) sA[t * 20 + m] = ex[m] * inv;
    }
    __syncthreads();

    // ---- phase 4: build fp16 B-fragments; one conflict-free b128 write/lane/tile ----
    {
        half8* frag = (half8*)smem;
        for (int tile = w; tile < NKT * NNT; tile += 16) {
            int kt = tile / 5, nt = tile - kt * 5;
            int c = nt * 16 + (l & 15);
            int n = c >> 2;
            int m = kt * 4 + (l >> 4);        // constant per lane: all 8 k share m
            float anm = sA[n * 20 + m];
            float4 wg0 = *(const float4*)&wagg[c * 8];
            float4 wg1 = *(const float4*)&wagg[c * 8 + 4];
            float v0 = anm * wg0.x, v1 = anm * wg0.y, v2 = anm * wg0.z, v3 = anm * wg0.w;
            float v4 = anm * wg1.x, v5 = anm * wg1.y, v6 = anm * wg1.z, v7 = anm * wg1.w;
            if (n == m) {
                float4 ws0 = *(const float4*)&wself[c * 8];
                float4 ws1 = *(const float4*)&wself[c * 8 + 4];
                v0 += ws0.x; v1 += ws0.y; v2 += ws0.z; v3 += ws0.w;
                v4 += ws1.x; v5 += ws1.y; v6 += ws1.z; v7 += ws1.w;
            }
            half8 hv;
            hv[0] = (_Float16)v0; hv[1] = (_Float16)v1; hv[2] = (_Float16)v2; hv[3] = (_Float16)v3;
            hv[4] = (_Float16)v4; hv[5] = (_Float16)v5; hv[6] = (_Float16)v6; hv[7] = (_Float16)v7;
            frag[tile * 64 + l] = hv;
        }
    }
    __syncthreads();

    // ---- main GEMM: 32 rows/wave, fp16 single-pass, 50 MFMAs/wave ----
    const half8* frag = (const half8*)smem;
    f32x4 acc[2][NNT];
    #pragma unroll
    for (int g = 0; g < 2; ++g)
        #pragma unroll
        for (int nt = 0; nt < NNT; ++nt) acc[g][nt] = (f32x4){0.f, 0.f, 0.f, 0.f};

    #pragma unroll
    for (int kt = 0; kt < NKT; ++kt) {
        float4 na0, nb0, na1, nb1;
        if (kt < NKT - 1) {
            na0 = *(const float4*)(xq0 + (kt + 1) * 32);
            nb0 = *(const float4*)(xq0 + (kt + 1) * 32 + 4);
            na1 = *(const float4*)(xq1 + (kt + 1) * 32);
            nb1 = *(const float4*)(xq1 + (kt + 1) * 32 + 4);
        }
        half8 a0 = cvt8(pa0, pb0);
        half8 a1 = cvt8(pa1, pb1);
        #pragma unroll
        for (int nt = 0; nt < NNT; ++nt) {
            half8 bh = frag[(kt * NNT + nt) * 64 + l];
            acc[0][nt] = __builtin_amdgcn_mfma_f32_16x16x32_f16(a0, bh, acc[0][nt], 0, 0, 0);
            acc[1][nt] = __builtin_amdgcn_mfma_f32_16x16x32_f16(a1, bh, acc[1][nt], 0, 0, 0);
        }
        pa0 = na0; pb0 = nb0; pa1 = na1; pb1 = nb1;
    }

    // ---- epilogue: 4 sub-passes (mt x q-pair), 128-row restage, coalesced stores ----
    const float lw0 = slin[0], lw1 = slin[1], lb = slin[2];
    __syncthreads();                     // all frag reads done before overwrite
    float* epi = (float*)smem;
    #pragma unroll
    for (int mt = 0; mt < 2; ++mt) {
        #pragma unroll
        for (int qb = 0; qb < 4; qb += 2) {
            #pragma unroll
            for (int nt = 0; nt < NNT; ++nt) {
                int c = nt * 16 + (l & 15);
                float bia = sbias[c];
                #pragma unroll
                for (int dq = 0; dq < 2; ++dq) {
                    int rc = w * 8 + ((l >> 4) << 1) + dq;   // 0..127
                    epi[rc * EPI_STRIDE + c] = acc[mt][nt][qb + dq] + bia;
                }
            }
            __syncthreads();
            #pragma unroll
            for (int o = t; o < EPI_ROWS * NN; o += THREADS) {   // 2560 outputs
                int rc = o / 20;
                int n = o - rc * 20;
                float4 p = *(const float4*)&epi[rc * EPI_STRIDE + n * 4];
                float i0 = 1.f / (1.f + __expf(p.x));
                float i1 = 1.f / (1.f + __expf(p.y));
                float t0 = 1.f - 2.f / (__expf(2.f * p.z) + 1.f);
                float t1 = 1.f - 2.f / (__expf(2.f * p.w) + 1.f);
                float h0 = i0 * t0;
                float h1 = i1 * t1;
                float yv = fmaxf(h0, 0.f) * lw0 + fmaxf(h1, 0.f) * lw1 + lb;
                size_t g = (size_t)blockIdx.x * ROWS_PER_BLOCK
                         + (size_t)(rc >> 3) * ROWS_PER_WAVE
                         + (size_t)mt * 16 + (((rc & 7) >> 1) << 2) + qb + (rc & 1);
                y[g * NN + n] = yv;
            }
            __syncthreads();
        }
    }
}

extern "C" void kernel_launch(void* const* d_in, const int* in_sizes, int n_in,
                              void* d_out, int out_size, void* d_ws, size_t ws_size,
                              hipStream_t stream) {
    const float* x      = (const float*)d_in[0];
    const float* e      = (const float*)d_in[1];
    const float* gate_w = (const float*)d_in[2];
    const float* gate_b = (const float*)d_in[3];
    const float* upd_w  = (const float*)d_in[4];
    const float* upd_b  = (const float*)d_in[5];
    const float* lin_w  = (const float*)d_in[6];
    const float* lin_b  = (const float*)d_in[7];
    float* y = (float*)d_out;

    const int Bn = in_sizes[0] / XROW;           // 131072
    const int nblocks = Bn / ROWS_PER_BLOCK;     // 256

    rgcn_fused<<<nblocks, THREADS, 0, stream>>>(x, e, gate_w, gate_b,
                                                upd_w, upd_b, lin_w, lin_b, y);
}

// Round 6
// 26.178 us; speedup vs baseline: 2.1656x; 1.1612x over previous
//
#include <hip/hip_runtime.h>
#include <math.h>

#define NN 20
#define ED 4
#define XROW 160
#define NC 80
#define NKT 5
#define NNT 5
#define FRAG_BYTES (NKT * NNT * 64 * 16)     // 25600
#define BIAS_OFF   FRAG_BYTES                // 25600
#define LIN_OFF    (BIAS_OFF + NC * 4)       // 25920
#define CONS_BYTES (LIN_OFF + 16)            // 25936
#define CONS_U4    (CONS_BYTES / 16)         // 1621
#define THREADS 512
#define ROWS_PER_WAVE 16
#define ROWS_PER_BLOCK 128                   // 8 waves * 16 rows
#define EPI_STRIDE 84                        // 64 rows * 84 * 4 = 21504 B (< FRAG_BYTES)

typedef __attribute__((ext_vector_type(8))) _Float16 half8;
typedef __attribute__((ext_vector_type(4))) float f32x4;
typedef __attribute__((ext_vector_type(4))) unsigned uint4v;

static __device__ __forceinline__ half8 cvt8(float4 a, float4 b) {
    half8 r;
    r[0] = (_Float16)a.x; r[1] = (_Float16)a.y; r[2] = (_Float16)a.z; r[3] = (_Float16)a.w;
    r[4] = (_Float16)b.x; r[5] = (_Float16)b.y; r[6] = (_Float16)b.z; r[7] = (_Float16)b.w;
    return r;
}

// ---------------- setup: fold everything into fp16 B-frag table in d_ws ------
__global__ void rgcn_setup(const float* __restrict__ e,
                           const float* __restrict__ gate_w,
                           const float* __restrict__ gate_b,
                           const float* __restrict__ upd_w,
                           const float* __restrict__ upd_b,
                           const float* __restrict__ lin_w,
                           const float* __restrict__ lin_b,
                           char* __restrict__ ws) {
    __shared__ float el[80];
    __shared__ float sA[400];
    __shared__ float wself[640];
    __shared__ float wagg[640];
    const int t = threadIdx.x;
    const int l = t & 63;
    const int w = t >> 6;

    if (t < NN * ED) el[t] = e[t];
    __syncthreads();

    if (t < 400) {
        int n = t / 20, m = t - (t / 20) * 20;
        float d = 0.f;
        for (int j = 0; j < ED; ++j) d += el[n * ED + j] * el[m * ED + j];
        sA[t] = fmaxf(d, 0.f);
    }
    for (int idx = t; idx < 1280; idx += THREADS) {
        int sel = idx >= 640;
        int rem = sel ? idx - 640 : idx;
        int c = rem >> 3, i = rem & 7;
        int n = c >> 2, ro = c & 3;
        float v = 0.f;
        if (ro < 2) {
            int o = 2 + ro;
            for (int d = 0; d < ED; ++d) v += el[n * ED + d] * gate_w[d * 80 + sel * 40 + i * 4 + o];
        } else {
            int o = ro - 2;
            for (int d = 0; d < ED; ++d) v += el[n * ED + d] * upd_w[d * 40 + sel * 20 + i * 2 + o];
        }
        (sel ? wagg : wself)[rem] = v;
    }
    float* wbias = (float*)(ws + BIAS_OFF);
    float* wlin  = (float*)(ws + LIN_OFF);
    if (t < NC) {
        int n = t >> 2, ro = t & 3;
        float b = 0.f;
        for (int d = 0; d < ED; ++d)
            b += el[n * ED + d] * (ro < 2 ? gate_b[d * 4 + 2 + ro] : upd_b[d * 2 + ro - 2]);
        wbias[t] = b;
    }
    if (t == 0) { wlin[0] = lin_w[0]; wlin[1] = lin_w[1]; wlin[2] = lin_b[0]; wlin[3] = 0.f; }
    __syncthreads();

    if (t < NN) {
        float mx = -1e30f;
        for (int m = 0; m < NN; ++m) mx = fmaxf(mx, sA[t * 20 + m]);
        float ex[NN]; float sum = 0.f;
        for (int m = 0; m < NN; ++m) { ex[m] = __expf(sA[t * 20 + m] - mx); sum += ex[m]; }
        float inv = 1.f / sum;
        for (int m = 0; m < NN; ++m) sA[t * 20 + m] = ex[m] * inv;
    }
    __syncthreads();

    half8* frag = (half8*)ws;
    for (int tile = w; tile < NKT * NNT; tile += (THREADS / 64)) {
        int kt = tile / 5, nt = tile - kt * 5;
        int c = nt * 16 + (l & 15);
        int n = c >> 2;
        int m = kt * 4 + (l >> 4);
        float anm = sA[n * 20 + m];
        float4 wg0 = *(const float4*)&wagg[c * 8];
        float4 wg1 = *(const float4*)&wagg[c * 8 + 4];
        float v0 = anm * wg0.x, v1 = anm * wg0.y, v2 = anm * wg0.z, v3 = anm * wg0.w;
        float v4 = anm * wg1.x, v5 = anm * wg1.y, v6 = anm * wg1.z, v7 = anm * wg1.w;
        if (n == m) {
            float4 ws0 = *(const float4*)&wself[c * 8];
            float4 ws1 = *(const float4*)&wself[c * 8 + 4];
            v0 += ws0.x; v1 += ws0.y; v2 += ws0.z; v3 += ws0.w;
            v4 += ws1.x; v5 += ws1.y; v6 += ws1.z; v7 += ws1.w;
        }
        half8 hv;
        hv[0] = (_Float16)v0; hv[1] = (_Float16)v1; hv[2] = (_Float16)v2; hv[3] = (_Float16)v3;
        hv[4] = (_Float16)v4; hv[5] = (_Float16)v5; hv[6] = (_Float16)v6; hv[7] = (_Float16)v7;
        frag[tile * 64 + l] = hv;
    }
}

// ---------------- main: burst-load x, fp16 MFMA, epilogue -------------------
__global__ __launch_bounds__(THREADS, 6) void rgcn_main(
        const float* __restrict__ x,
        const char* __restrict__ cons,
        float* __restrict__ y) {
    __shared__ __align__(16) char smem[CONS_BYTES];
    const int t = threadIdx.x;
    const int l = t & 63;
    const int w = t >> 6;

    // full x burst for this wave's 16 rows: 10 float4 in flight before any compute
    const size_t row0 = (size_t)blockIdx.x * ROWS_PER_BLOCK + (size_t)w * ROWS_PER_WAVE;
    const float* xp = x + (row0 + (l & 15)) * XROW + ((l >> 4) << 3);
    float4 xa0 = *(const float4*)(xp);       float4 xb0 = *(const float4*)(xp + 4);
    float4 xa1 = *(const float4*)(xp + 32);  float4 xb1 = *(const float4*)(xp + 36);
    float4 xa2 = *(const float4*)(xp + 64);  float4 xb2 = *(const float4*)(xp + 68);
    float4 xa3 = *(const float4*)(xp + 96);  float4 xb3 = *(const float4*)(xp + 100);
    float4 xa4 = *(const float4*)(xp + 128); float4 xb4 = *(const float4*)(xp + 132);

    // cons table -> LDS (26 KB, L2-resident, coalesced)
    {
        const uint4v* src = (const uint4v*)cons;
        uint4v* dst = (uint4v*)smem;
        #pragma unroll
        for (int i = t; i < CONS_U4; i += THREADS) dst[i] = src[i];
    }
    __syncthreads();

    const half8* frag = (const half8*)smem;
    const float* sbias = (const float*)(smem + BIAS_OFF);
    const float* slin  = (const float*)(smem + LIN_OFF);

    f32x4 acc[NNT];
    #pragma unroll
    for (int nt = 0; nt < NNT; ++nt) acc[nt] = (f32x4){0.f, 0.f, 0.f, 0.f};

    #define STEP(XA, XB, KT)                                                        \
    {                                                                               \
        half8 a = cvt8(XA, XB);                                                     \
        _Pragma("unroll")                                                           \
        for (int nt = 0; nt < NNT; ++nt) {                                          \
            half8 bh = frag[((KT) * NNT + nt) * 64 + l];                            \
            acc[nt] = __builtin_amdgcn_mfma_f32_16x16x32_f16(a, bh, acc[nt], 0, 0, 0); \
        }                                                                           \
    }
    STEP(xa0, xb0, 0)
    STEP(xa1, xb1, 1)
    STEP(xa2, xb2, 2)
    STEP(xa3, xb3, 3)
    STEP(xa4, xb4, 4)
    #undef STEP

    // epilogue: 2 sub-passes of 64 rows restaged in LDS (reuses frag region)
    const float lw0 = slin[0], lw1 = slin[1], lb = slin[2];
    __syncthreads();
    float* epi = (float*)smem;
    #pragma unroll
    for (int qb = 0; qb < 4; qb += 2) {
        #pragma unroll
        for (int nt = 0; nt < NNT; ++nt) {
            int c = nt * 16 + (l & 15);
            float bia = sbias[c];
            #pragma unroll
            for (int dq = 0; dq < 2; ++dq) {
                int rc = w * 8 + ((l >> 4) << 1) + dq;    // 0..63
                epi[rc * EPI_STRIDE + c] = acc[nt][qb + dq] + bia;
            }
        }
        __syncthreads();
        #pragma unroll
        for (int o = t; o < 64 * NN; o += THREADS) {      // 1280 outputs
            int rc = o / 20;
            int n = o - rc * 20;
            float4 p = *(const float4*)&epi[rc * EPI_STRIDE + n * 4];
            float e0 = __expf(p.x);
            float e1 = __expf(p.y);
            float i0 = __builtin_amdgcn_rcpf(1.f + e0);
            float i1 = __builtin_amdgcn_rcpf(1.f + e1);
            float t0 = 1.f - 2.f * __builtin_amdgcn_rcpf(__expf(2.f * p.z) + 1.f);
            float t1 = 1.f - 2.f * __builtin_amdgcn_rcpf(__expf(2.f * p.w) + 1.f);
            float h0 = i0 * t0;
            float h1 = i1 * t1;
            float yv = fmaxf(h0, 0.f) * lw0 + fmaxf(h1, 0.f) * lw1 + lb;
            size_t g = (size_t)blockIdx.x * ROWS_PER_BLOCK
                     + (size_t)(rc >> 3) * ROWS_PER_WAVE
                     + (((rc & 7) >> 1) << 2) + qb + (rc & 1);
            y[g * NN + n] = yv;
        }
        __syncthreads();
    }
}

extern "C" void kernel_launch(void* const* d_in, const int* in_sizes, int n_in,
                              void* d_out, int out_size, void* d_ws, size_t ws_size,
                              hipStream_t stream) {
    const float* x      = (const float*)d_in[0];
    const float* e      = (const float*)d_in[1];
    const float* gate_w = (const float*)d_in[2];
    const float* gate_b = (const float*)d_in[3];
    const float* upd_w  = (const float*)d_in[4];
    const float* upd_b  = (const float*)d_in[5];
    const float* lin_w  = (const float*)d_in[6];
    const float* lin_b  = (const float*)d_in[7];
    char* cons = (char*)d_ws;
    float* y   = (float*)d_out;

    const int Bn = in_sizes[0] / XROW;           // 131072
    const int nblocks = Bn / ROWS_PER_BLOCK;     // 1024

    rgcn_setup<<<1, THREADS, 0, stream>>>(e, gate_w, gate_b, upd_w, upd_b,
                                          lin_w, lin_b, cons);
    rgcn_main<<<nblocks, THREADS, 0, stream>>>(x, cons, y);
}